// Round 12
// baseline (243.951 us; speedup 1.0000x reference)
//
#include <hip/hip_runtime.h>
#include <stdint.h>

typedef unsigned long long ull;
typedef unsigned short u16;

#define Bc 8
#define Cc 64
#define Hc 256
#define Wc 256
#define Vc (Hc*Wc)            // 65536
#define REc ((Hc-1)*Wc)       // 65280 row (down) edges
#define Ec (REc + Hc*(Wc-1))  // 130560 total edges
#define VM1 (Vc-1)            // 65535
#define INF64 0xFFFFFFFFFFFFFFFFull
#define TS 32                 // tile side
#define NRND 14               // global rounds r=1..13; 13 hooks cover <=8192 comps (bound 7936)
#define EPB 8192              // edges per block in compaction
#define BPB 16                // blocks per batch

__device__ __forceinline__ void edge_uv(int e, int& u, int& v){
  if (e < REc){ u = e; v = e + Wc; }
  else { int k = e - REc; int i = k / (Wc-1); int j = k - i*(Wc-1); u = i*Wc + j; v = u + 1; }
}

__device__ __forceinline__ ull packw(float w, int e){
  return ((ull)__float_as_uint(w) << 32) | (unsigned)e;
}

__device__ __forceinline__ int chase(const int* __restrict__ parB, int x){
  int p = parB[x];
  while (p != x){ x = p; p = parB[x]; }
  return x;
}

// ---------------- stage 1: weights (neighbor-sum sharing) + tile-local Boruvka ----------------
// One WG per 32x32 tile. Each thread computes only its D/R edge sums; U/L sums come
// from the neighbor thread's D/R via LDS ((a-b)^2 == (b-a)^2 bitwise, same c order).
// Freeze rule (R7/R10-proven): a component selects/hooks only if its min incident
// edge is tile-internal (cut property => globally correct MST edges).
__global__ void __launch_bounds__(1024)
k_stage1(const float* __restrict__ g, float* __restrict__ wf,
         int* __restrict__ L, int* __restrict__ par, ull* __restrict__ b1,
         unsigned char* __restrict__ sel, int* __restrict__ act, int* __restrict__ outp){
  const int blk = blockIdx.x;
  const int b = blk >> 6, tile = blk & 63;
  const int ty = tile >> 3, tx = tile & 7;
  const int tid = threadIdx.x;
  const int li = tid >> 5, lj = tid & 31;
  const int i = ty*TS + li, j = tx*TS + lj;
  const int v = (i << 8) | j;

  const bool hU = i > 0, hD = i < Hc-1, hL = j > 0, hR = j < Wc-1;
  const int oD = hD ? Wc : 0, oR = hR ? 1 : 0;             // clamped: no OOB
  const bool needU = (li == 0) && hU;                      // tile-top row: own U-sum
  const bool needL = (lj == 0) && hL;                      // tile-left col: own L-sum
  const float* p = g + (size_t)b*Cc*Vc + v;
  float sD=0.f, sR=0.f, sUx=0.f, sLx=0.f;
  #pragma unroll 4
  for (int c = 0; c < Cc; ++c){                            // sequential c order (bit-exact)
    const float* pc = p + (size_t)c*Vc;
    float x = pc[0];
    float dD = x - pc[oD]; float dR = x - pc[oR];
    sD += dD*dD; sR += dR*dR;
    if (needU){ float du = x - pc[-Wc]; sUx += du*du; }
    if (needL){ float dl = x - pc[-1];  sLx += dl*dl; }
  }
  __shared__ float sDsh[1024], sRsh[1024];
  sDsh[tid] = sD; sRsh[tid] = sR;
  __syncthreads();
  const float sU = (li > 0) ? sDsh[tid-TS] : sUx;          // valid iff hU
  const float sL = (lj > 0) ? sRsh[tid-1 ] : sLx;          // valid iff hL

  const int eU = v - Wc, eD = v, eL = REc + i*(Wc-1) + j - 1, eR = REc + i*(Wc-1) + j;
  const ull pU = packw(sU+1.f, eU), pD = packw(sD+1.f, eD);
  const ull pL = packw(sL+1.f, eL), pR = packw(sR+1.f, eR);
  float* wfb = wf + (size_t)b*Ec;
  unsigned char* selb = sel + (size_t)b*Ec;
  if (hD){ wfb[eD] = sD+1.f; selb[eD] = 0; }               // canonical owner writes
  if (hR){ wfb[eR] = sR+1.f; selb[eR] = 0; }
  { int gt = blk*1024 + tid;
    if (gt < Bc*VM1){ outp[2*gt] = 0; outp[2*gt+1] = Wc; } // ref fill value (edge 0)
    if (gt < (NRND+2)*Bc) act[gt] = (gt >= Bc && gt < 2*Bc) ? 1 : 0; // act[1][*]=1
  }

  // --- tile-local Boruvka with freeze rule (R7/R10-verified) ---
  __shared__ u16 lab[1024];
  __shared__ u16 spar[1024];
  __shared__ ull best[1024];
  __shared__ int s_any;
  lab[tid] = (u16)tid;

  for (int round = 0; round < 16; ++round){
    best[tid] = INF64;
    if (tid == 0) s_any = 0;
    __syncthreads();
    int c = lab[tid];
    ull m = INF64;
    if (hU){ bool inc = (li > 0)    ? (lab[tid-TS] != c) : true; if (inc && pU < m) m = pU; }
    if (hD){ bool inc = (li < TS-1) ? (lab[tid+TS] != c) : true; if (inc && pD < m) m = pD; }
    if (hL){ bool inc = (lj > 0)    ? (lab[tid-1 ] != c) : true; if (inc && pL < m) m = pL; }
    if (hR){ bool inc = (lj < TS-1) ? (lab[tid+1 ] != c) : true; if (inc && pR < m) m = pR; }
    if (m != INF64) atomicMin(&best[c], m);
    __syncthreads();
    int pr = tid;
    if (c == tid){                                         // root of a live component
      ull pb = best[tid];
      if (pb != INF64){
        int e = (int)(unsigned)pb; int eu, ev; edge_uv(e, eu, ev);
        int diu = (eu>>8) - ty*TS, dju = (eu&255) - tx*TS;
        int div_ = (ev>>8) - ty*TS, djv = (ev&255) - tx*TS;
        bool inu  = ((unsigned)diu < TS) && ((unsigned)dju < TS);
        bool inv_ = ((unsigned)div_ < TS) && ((unsigned)djv < TS);
        if (inu && inv_){                                  // internal: select + hook
          int lu = diu*TS + dju, lv = div_*TS + djv;
          int cu = lab[lu], cv = lab[lv];
          int other = (cu == tid) ? cv : cu;
          sel[(size_t)b*Ec + e] = 1;
          s_any = 1;
          pr = (best[other] == pb && tid < other) ? tid : other;
        }                                                  // else boundary: freeze
      }
    }
    spar[tid] = (u16)pr;
    __syncthreads();
    int x = lab[tid];
    int pp = spar[x];
    while (pp != x){ x = pp; pp = spar[x]; }               // read-only chase, acyclic
    int any = s_any;
    lab[tid] = (u16)x;
    __syncthreads();
    if (!any) break;
  }

  // --- tail: int labels (global root vertex id), identity par, INF b1 ---
  int rt = lab[tid];
  int groot = ((ty*TS + (rt>>5)) << 8) | (tx*TS + (rt&31));
  const int t = (b << 16) | v;
  L[t] = groot;                                            // root vertex has L[t]==v
  par[t] = v;                                              // identity hook forest
  b1[t] = INF64;                                           // round-1 minima buffer
}

// rounds >=1 (R6-proven): fused {relabel to hook-forest root} + {vertex scan},
// root-only reset of next buffer, settled-interior fast path.
__global__ void __launch_bounds__(1024)
k_scanmerge(const float* __restrict__ wf, int* __restrict__ L,
            const int* __restrict__ par,
            ull* __restrict__ bcur, ull* __restrict__ bnxt,
            const int* __restrict__ act, int r){
  int t = blockIdx.x*1024 + threadIdx.x;
  int b = t >> 16;
  if (!act[r*Bc + b]) return;
  int v = t & VM1; const int base = b << 16;
  const int* parB = par + base;
  int Lt0 = L[t];
  int i = v >> 8, j = v & (Wc-1);
  int Lu = (i > 0)    ? L[base + v - Wc] : Lt0;
  int Ld = (i < Hc-1) ? L[base + v + Wc] : Lt0;
  int Ll = (j > 0)    ? L[base + v - 1 ] : Lt0;
  int Lr = (j < Wc-1) ? L[base + v + 1 ] : Lt0;
  if ((Lu==Lt0) & (Ld==Lt0) & (Ll==Lt0) & (Lr==Lt0)){      // settled neighborhood
    if (Lt0 != v) return;                                  // interior non-root: done
    if (parB[v] == v){ bnxt[t] = INF64; return; }          // true root: reset next buf
    /* dead root (stale self-label): fall through to refresh L */
  }
  int rt = chase(parB, Lt0);
  if (rt != Lt0) L[t] = rt;                                // racy-read-benign: readers re-chase
  if (v == rt) bnxt[t] = INF64;                            // root-only reset for round r+1
  const float* wfb = wf + (size_t)b*Ec;
  ull m = INF64;
  if (Lu != Lt0 && Lu != rt && chase(parB, Lu) != rt){
    int e = v - Wc; ull x = packw(wfb[e], e); if (x < m) m = x; }
  if (Ld != Lt0 && Ld != rt && chase(parB, Ld) != rt){
    int e = v;      ull x = packw(wfb[e], e); if (x < m) m = x; }
  if (Ll != Lt0 && Ll != rt && chase(parB, Ll) != rt){
    int e = REc + i*(Wc-1) + j - 1; ull x = packw(wfb[e], e); if (x < m) m = x; }
  if (Lr != Lt0 && Lr != rt && chase(parB, Lr) != rt){
    int e = REc + i*(Wc-1) + j;     ull x = packw(wfb[e], e); if (x < m) m = x; }
  if (m != INF64) atomicMin(&bcur[base + rt], m);
}

// roots pick best edge, mutual-pair break (smaller id stays root), write par + sel
__global__ void __launch_bounds__(1024)
k_hook(const int* __restrict__ L, const ull* __restrict__ bcur,
       int* __restrict__ par, unsigned char* __restrict__ sel, int* __restrict__ act, int r){
  int t = blockIdx.x*1024 + threadIdx.x;
  int b = t >> 16;
  if (!act[r*Bc + b]) return;
  int v = t & VM1;
  if (L[t] != v) return;                                   // roots only (L fresh for roots)
  const int base = b << 16;
  ull p = bcur[t];
  int pr = v;
  if (p != INF64){
    int e = (int)(unsigned)p; int eu, ev; edge_uv(e, eu, ev);
    int cu = L[base + eu], cv = L[base + ev];
    int other = (cu == v) ? cv : cu;
    sel[(size_t)b*Ec + e] = 1;
    if (act[(r+1)*Bc + b] == 0) act[(r+1)*Bc + b] = 1;     // read-guarded, benign race
    pr = (bcur[base + other] == p && v < other) ? v : other;
  }
  par[t] = pr;
}

// ---- ordered output compaction: count -> scatter (R6-proven) ----
__global__ void __launch_bounds__(1024)
k_cnt(const unsigned char* __restrict__ sel, int* __restrict__ blkcnt){
  int blk = blockIdx.x; int bb = blk / BPB; int kb = blk % BPB;
  int base = kb*EPB;
  int off = threadIdx.x * 8;
  int c = 0;
  if (base + off < Ec){
    const unsigned int* p = (const unsigned int*)(sel + (size_t)bb*Ec + base + off);
    unsigned int s = p[0] + p[1];                          // per-byte sums <=2, no carry
    c = (s & 0xFF) + ((s>>8)&0xFF) + ((s>>16)&0xFF) + (s>>24);
  }
  int lane = threadIdx.x & 63, wave = threadIdx.x >> 6;
  #pragma unroll
  for (int o = 32; o; o >>= 1) c += __shfl_down(c, o, 64);
  __shared__ int sw[16];
  if (lane == 0) sw[wave] = c;
  __syncthreads();
  if (threadIdx.x == 0){
    int s = 0;
    #pragma unroll
    for (int w = 0; w < 16; ++w) s += sw[w];
    blkcnt[blk] = s;
  }
}

__global__ void __launch_bounds__(1024)
k_scatter(const unsigned char* __restrict__ sel, const int* __restrict__ blkcnt,
          int* __restrict__ outp){
  int blk = blockIdx.x; int bb = blk / BPB; int kb = blk % BPB;
  __shared__ int s_boff;
  if (threadIdx.x < 64){                                   // wave 0: prefix of batch counts
    int c = ((int)threadIdx.x < kb) ? blkcnt[bb*BPB + threadIdx.x] : 0;
    #pragma unroll
    for (int o = 32; o; o >>= 1) c += __shfl_down(c, o, 64);
    if (threadIdx.x == 0) s_boff = c;
  }
  int base = kb*EPB;
  int off = threadIdx.x * 8;
  unsigned int a = 0, d = 0; int c = 0;
  if (base + off < Ec){
    const unsigned int* p = (const unsigned int*)(sel + (size_t)bb*Ec + base + off);
    a = p[0]; d = p[1];
    unsigned int s = a + d;
    c = (s & 0xFF) + ((s>>8)&0xFF) + ((s>>16)&0xFF) + (s>>24);
  }
  int lane = threadIdx.x & 63, wave = threadIdx.x >> 6;
  int x = c;
  #pragma unroll
  for (int o = 1; o < 64; o <<= 1){ int y = __shfl_up(x, o, 64); if (lane >= o) x += y; }
  __shared__ int sw[16];
  if (lane == 63) sw[wave] = x;
  __syncthreads();
  int woff = 0;
  #pragma unroll
  for (int w = 0; w < 16; ++w) if (w < wave) woff += sw[w];
  int pos = s_boff + woff + x - c;
  if (base + off < Ec){
    int* ob = outp + (size_t)bb*VM1*2;
    int ebase = base + off;
    #pragma unroll
    for (int k = 0; k < 8; ++k){
      unsigned int byte = ((k < 4) ? (a >> (8*k)) : (d >> (8*(k-4)))) & 0xFF;
      if (byte){ int e = ebase + k; int u, v; edge_uv(e, u, v); ob[2*pos] = u; ob[2*pos+1] = v; ++pos; }
    }
  }
}

extern "C" void kernel_launch(void* const* d_in, const int* in_sizes, int n_in,
                              void* d_out, int out_size, void* d_ws, size_t ws_size,
                              hipStream_t stream) {
  const float* g = (const float*)d_in[0];
  int* outp = (int*)d_out;

  char* ws = (char*)d_ws;
  size_t off = 0;
  auto alloc = [&](size_t bytes) -> void* {
    void* p = ws + off; off += (bytes + 511) & ~(size_t)511; return p;
  };
  ull* b0 = (ull*)alloc((size_t)Bc*Vc*8);
  ull* b1 = (ull*)alloc((size_t)Bc*Vc*8);
  float* wf = (float*)alloc((size_t)Bc*Ec*4);
  int* L   = (int*)alloc((size_t)Bc*Vc*4);
  int* par = (int*)alloc((size_t)Bc*Vc*4);
  unsigned char* sel = (unsigned char*)alloc((size_t)Bc*Ec);
  int* act  = (int*)alloc((size_t)(NRND+2)*Bc*4);
  int* blkcnt = (int*)alloc((size_t)Bc*BPB*4);

  const int gv = (Bc*Vc)/1024;                             // 512 WGs, 1024-thr

  k_stage1<<<Bc*64, 1024, 0, stream>>>(g, wf, L, par, b1, sel, act, outp);
  for (int r = 1; r < NRND; ++r){
    ull* bcur = (r & 1) ? b1 : b0;                         // r=1 -> b1 (INF-init by stage1)
    ull* bnxt = (r & 1) ? b0 : b1;
    k_scanmerge<<<gv, 1024, 0, stream>>>(wf, L, par, bcur, bnxt, act, r);
    k_hook     <<<gv, 1024, 0, stream>>>(L, bcur, par, sel, act, r);
  }
  k_cnt    <<<Bc*BPB, 1024, 0, stream>>>(sel, blkcnt);
  k_scatter<<<Bc*BPB, 1024, 0, stream>>>(sel, blkcnt, outp);
}

// Round 13
// 235.230 us; speedup vs baseline: 1.0371x; 1.0371x over previous
//
#include <hip/hip_runtime.h>
#include <stdint.h>

typedef unsigned long long ull;
typedef unsigned short u16;

#define Bc 8
#define Cc 64
#define Hc 256
#define Wc 256
#define Vc (Hc*Wc)            // 65536
#define REc ((Hc-1)*Wc)       // 65280 row (down) edges
#define Ec (REc + Hc*(Wc-1))  // 130560 total edges
#define VM1 (Vc-1)            // 65535
#define INF64 0xFFFFFFFFFFFFFFFFull
#define TS 32                 // tile side
#define NRND 14               // rounds r=1..13: 13 hooks cover <=7936 comps (124/tile bound)
#define EPB 8192              // edges per block in compaction
#define BPB 16                // blocks per batch

__device__ __forceinline__ void edge_uv(int e, int& u, int& v){
  if (e < REc){ u = e; v = e + Wc; }
  else { int k = e - REc; int i = k / (Wc-1); int j = k - i*(Wc-1); u = i*Wc + j; v = u + 1; }
}

__device__ __forceinline__ ull packw(float w, int e){
  return ((ull)__float_as_uint(w) << 32) | (unsigned)e;
}

__device__ __forceinline__ int chase(const int* __restrict__ parB, int x){
  int p = parB[x];
  while (p != x){ x = p; p = parB[x]; }
  return x;
}

// ---------------- stage 1 (R10-proven verbatim): weights + tile-local Boruvka ----------------
// One WG per 32x32 tile. Freeze rule: a component selects/hooks only if its min
// incident edge is tile-internal (cut property => globally correct MST edges).
__global__ void __launch_bounds__(1024)
k_stage1(const float* __restrict__ g, float* __restrict__ wf,
         int* __restrict__ L, int* __restrict__ par, ull* __restrict__ b1,
         unsigned char* __restrict__ sel, int* __restrict__ act, int* __restrict__ outp){
  const int blk = blockIdx.x;
  const int b = blk >> 6, tile = blk & 63;
  const int ty = tile >> 3, tx = tile & 7;
  const int tid = threadIdx.x;
  const int li = tid >> 5, lj = tid & 31;
  const int i = ty*TS + li, j = tx*TS + lj;
  const int v = (i << 8) | j;

  // --- 4-direction edge weights (sequential c order: bit-exact vs reference) ---
  const bool hU = i > 0, hD = i < Hc-1, hL = j > 0, hR = j < Wc-1;
  const int oU = hU ? -Wc : 0, oD = hD ? Wc : 0, oL = hL ? -1 : 0, oR = hR ? 1 : 0;
  const float* p = g + (size_t)b*Cc*Vc + v;
  float sU=0.f, sD=0.f, sL=0.f, sR=0.f;
  #pragma unroll 4
  for (int c = 0; c < Cc; ++c){
    const float* pc = p + (size_t)c*Vc;
    float x = pc[0];
    float dU = x - pc[oU]; float dD = x - pc[oD];          // (a-b)^2 == (b-a)^2 bitwise
    float dL = x - pc[oL]; float dR = x - pc[oR];
    sU += dU*dU; sD += dD*dD; sL += dL*dL; sR += dR*dR;
  }
  const int eU = v - Wc, eD = v, eL = REc + i*(Wc-1) + j - 1, eR = REc + i*(Wc-1) + j;
  const ull pU = packw(sU+1.f, eU), pD = packw(sD+1.f, eD);
  const ull pL = packw(sL+1.f, eL), pR = packw(sR+1.f, eR);
  float* wfb = wf + (size_t)b*Ec;
  unsigned char* selb = sel + (size_t)b*Ec;
  if (hD){ wfb[eD] = sD+1.f; selb[eD] = 0; }               // canonical owner writes
  if (hR){ wfb[eR] = sR+1.f; selb[eR] = 0; }
  { int gt = blk*1024 + tid;
    if (gt < Bc*VM1){ outp[2*gt] = 0; outp[2*gt+1] = Wc; } // ref fill value (edge 0)
    if (gt < (NRND+2)*Bc) act[gt] = (gt >= Bc && gt < 2*Bc) ? 1 : 0; // act[1][*]=1
  }

  // --- tile-local Boruvka with freeze rule (R7/R10-verified) ---
  __shared__ u16 lab[1024];
  __shared__ u16 spar[1024];
  __shared__ ull best[1024];
  __shared__ int s_any;
  lab[tid] = (u16)tid;

  for (int round = 0; round < 16; ++round){
    best[tid] = INF64;
    if (tid == 0) s_any = 0;
    __syncthreads();
    int c = lab[tid];
    ull m = INF64;
    if (hU){ bool inc = (li > 0)    ? (lab[tid-TS] != c) : true; if (inc && pU < m) m = pU; }
    if (hD){ bool inc = (li < TS-1) ? (lab[tid+TS] != c) : true; if (inc && pD < m) m = pD; }
    if (hL){ bool inc = (lj > 0)    ? (lab[tid-1 ] != c) : true; if (inc && pL < m) m = pL; }
    if (hR){ bool inc = (lj < TS-1) ? (lab[tid+1 ] != c) : true; if (inc && pR < m) m = pR; }
    if (m != INF64) atomicMin(&best[c], m);
    __syncthreads();
    int pr = tid;
    if (c == tid){                                         // root of a live component
      ull pb = best[tid];
      if (pb != INF64){
        int e = (int)(unsigned)pb; int eu, ev; edge_uv(e, eu, ev);
        int diu = (eu>>8) - ty*TS, dju = (eu&255) - tx*TS;
        int div_ = (ev>>8) - ty*TS, djv = (ev&255) - tx*TS;
        bool inu  = ((unsigned)diu < TS) && ((unsigned)dju < TS);
        bool inv_ = ((unsigned)div_ < TS) && ((unsigned)djv < TS);
        if (inu && inv_){                                  // internal: select + hook
          int lu = diu*TS + dju, lv = div_*TS + djv;
          int cu = lab[lu], cv = lab[lv];
          int other = (cu == tid) ? cv : cu;
          sel[(size_t)b*Ec + e] = 1;
          s_any = 1;
          pr = (best[other] == pb && tid < other) ? tid : other;
        }                                                  // else boundary: freeze
      }
    }
    spar[tid] = (u16)pr;
    __syncthreads();
    int x = lab[tid];
    int pp = spar[x];
    while (pp != x){ x = pp; pp = spar[x]; }               // read-only chase, acyclic
    int any = s_any;
    lab[tid] = (u16)x;
    __syncthreads();
    if (!any) break;
  }

  // --- tail: int labels (global root vertex id), identity par, INF b1 ---
  int rt = lab[tid];
  int groot = ((ty*TS + (rt>>5)) << 8) | (tx*TS + (rt&31));
  const int t = (b << 16) | v;
  L[t] = groot;                                            // root vertex has L[t]==v
  par[t] = v;                                              // identity hook forest
  b1[t] = INF64;                                           // round-1 minima buffer
}

// rounds >=1 (R6-proven): fused {relabel to hook-forest root} + {vertex scan},
// root-only reset of next buffer, settled-interior fast path.
__global__ void __launch_bounds__(1024)
k_scanmerge(const float* __restrict__ wf, int* __restrict__ L,
            const int* __restrict__ par,
            ull* __restrict__ bcur, ull* __restrict__ bnxt,
            const int* __restrict__ act, int r){
  int t = blockIdx.x*1024 + threadIdx.x;
  int b = t >> 16;
  if (!act[r*Bc + b]) return;
  int v = t & VM1; const int base = b << 16;
  const int* parB = par + base;
  int Lt0 = L[t];
  int i = v >> 8, j = v & (Wc-1);
  int Lu = (i > 0)    ? L[base + v - Wc] : Lt0;
  int Ld = (i < Hc-1) ? L[base + v + Wc] : Lt0;
  int Ll = (j > 0)    ? L[base + v - 1 ] : Lt0;
  int Lr = (j < Wc-1) ? L[base + v + 1 ] : Lt0;
  if ((Lu==Lt0) & (Ld==Lt0) & (Ll==Lt0) & (Lr==Lt0)){      // settled neighborhood
    if (Lt0 != v) return;                                  // interior non-root: done
    if (parB[v] == v){ bnxt[t] = INF64; return; }          // true root: reset next buf
    /* dead root (stale self-label): fall through to refresh L */
  }
  int rt = chase(parB, Lt0);
  if (rt != Lt0) L[t] = rt;                                // racy-read-benign: readers re-chase
  if (v == rt) bnxt[t] = INF64;                            // root-only reset for round r+1
  const float* wfb = wf + (size_t)b*Ec;
  ull m = INF64;
  if (Lu != Lt0 && Lu != rt && chase(parB, Lu) != rt){
    int e = v - Wc; ull x = packw(wfb[e], e); if (x < m) m = x; }
  if (Ld != Lt0 && Ld != rt && chase(parB, Ld) != rt){
    int e = v;      ull x = packw(wfb[e], e); if (x < m) m = x; }
  if (Ll != Lt0 && Ll != rt && chase(parB, Ll) != rt){
    int e = REc + i*(Wc-1) + j - 1; ull x = packw(wfb[e], e); if (x < m) m = x; }
  if (Lr != Lt0 && Lr != rt && chase(parB, Lr) != rt){
    int e = REc + i*(Wc-1) + j;     ull x = packw(wfb[e], e); if (x < m) m = x; }
  if (m != INF64) atomicMin(&bcur[base + rt], m);
}

// roots pick best edge, mutual-pair break (smaller id stays root), write par + sel
__global__ void __launch_bounds__(1024)
k_hook(const int* __restrict__ L, const ull* __restrict__ bcur,
       int* __restrict__ par, unsigned char* __restrict__ sel, int* __restrict__ act, int r){
  int t = blockIdx.x*1024 + threadIdx.x;
  int b = t >> 16;
  if (!act[r*Bc + b]) return;
  int v = t & VM1;
  if (L[t] != v) return;                                   // roots only (L fresh for roots)
  const int base = b << 16;
  ull p = bcur[t];
  int pr = v;
  if (p != INF64){
    int e = (int)(unsigned)p; int eu, ev; edge_uv(e, eu, ev);
    int cu = L[base + eu], cv = L[base + ev];
    int other = (cu == v) ? cv : cu;
    sel[(size_t)b*Ec + e] = 1;
    if (act[(r+1)*Bc + b] == 0) act[(r+1)*Bc + b] = 1;     // read-guarded, benign race
    pr = (bcur[base + other] == p && v < other) ? v : other;
  }
  par[t] = pr;
}

// ---- ordered output compaction: count -> scatter (R6-proven) ----
__global__ void __launch_bounds__(1024)
k_cnt(const unsigned char* __restrict__ sel, int* __restrict__ blkcnt){
  int blk = blockIdx.x; int bb = blk / BPB; int kb = blk % BPB;
  int base = kb*EPB;
  int off = threadIdx.x * 8;
  int c = 0;
  if (base + off < Ec){
    const unsigned int* p = (const unsigned int*)(sel + (size_t)bb*Ec + base + off);
    unsigned int s = p[0] + p[1];                          // per-byte sums <=2, no carry
    c = (s & 0xFF) + ((s>>8)&0xFF) + ((s>>16)&0xFF) + (s>>24);
  }
  int lane = threadIdx.x & 63, wave = threadIdx.x >> 6;
  #pragma unroll
  for (int o = 32; o; o >>= 1) c += __shfl_down(c, o, 64);
  __shared__ int sw[16];
  if (lane == 0) sw[wave] = c;
  __syncthreads();
  if (threadIdx.x == 0){
    int s = 0;
    #pragma unroll
    for (int w = 0; w < 16; ++w) s += sw[w];
    blkcnt[blk] = s;
  }
}

__global__ void __launch_bounds__(1024)
k_scatter(const unsigned char* __restrict__ sel, const int* __restrict__ blkcnt,
          int* __restrict__ outp){
  int blk = blockIdx.x; int bb = blk / BPB; int kb = blk % BPB;
  __shared__ int s_boff;
  if (threadIdx.x < 64){                                   // wave 0: prefix of batch counts
    int c = ((int)threadIdx.x < kb) ? blkcnt[bb*BPB + threadIdx.x] : 0;
    #pragma unroll
    for (int o = 32; o; o >>= 1) c += __shfl_down(c, o, 64);
    if (threadIdx.x == 0) s_boff = c;
  }
  int base = kb*EPB;
  int off = threadIdx.x * 8;
  unsigned int a = 0, d = 0; int c = 0;
  if (base + off < Ec){
    const unsigned int* p = (const unsigned int*)(sel + (size_t)bb*Ec + base + off);
    a = p[0]; d = p[1];
    unsigned int s = a + d;
    c = (s & 0xFF) + ((s>>8)&0xFF) + ((s>>16)&0xFF) + (s>>24);
  }
  int lane = threadIdx.x & 63, wave = threadIdx.x >> 6;
  int x = c;
  #pragma unroll
  for (int o = 1; o < 64; o <<= 1){ int y = __shfl_up(x, o, 64); if (lane >= o) x += y; }
  __shared__ int sw[16];
  if (lane == 63) sw[wave] = x;
  __syncthreads();
  int woff = 0;
  #pragma unroll
  for (int w = 0; w < 16; ++w) if (w < wave) woff += sw[w];
  int pos = s_boff + woff + x - c;
  if (base + off < Ec){
    int* ob = outp + (size_t)bb*VM1*2;
    int ebase = base + off;
    #pragma unroll
    for (int k = 0; k < 8; ++k){
      unsigned int byte = ((k < 4) ? (a >> (8*k)) : (d >> (8*(k-4)))) & 0xFF;
      if (byte){ int e = ebase + k; int u, v; edge_uv(e, u, v); ob[2*pos] = u; ob[2*pos+1] = v; ++pos; }
    }
  }
}

extern "C" void kernel_launch(void* const* d_in, const int* in_sizes, int n_in,
                              void* d_out, int out_size, void* d_ws, size_t ws_size,
                              hipStream_t stream) {
  const float* g = (const float*)d_in[0];
  int* outp = (int*)d_out;

  char* ws = (char*)d_ws;
  size_t off = 0;
  auto alloc = [&](size_t bytes) -> void* {
    void* p = ws + off; off += (bytes + 511) & ~(size_t)511; return p;
  };
  ull* b0 = (ull*)alloc((size_t)Bc*Vc*8);
  ull* b1 = (ull*)alloc((size_t)Bc*Vc*8);
  float* wf = (float*)alloc((size_t)Bc*Ec*4);
  int* L   = (int*)alloc((size_t)Bc*Vc*4);
  int* par = (int*)alloc((size_t)Bc*Vc*4);
  unsigned char* sel = (unsigned char*)alloc((size_t)Bc*Ec);
  int* act  = (int*)alloc((size_t)(NRND+2)*Bc*4);
  int* blkcnt = (int*)alloc((size_t)Bc*BPB*4);

  const int gv = (Bc*Vc)/1024;                             // 512 WGs, 1024-thr

  k_stage1<<<Bc*64, 1024, 0, stream>>>(g, wf, L, par, b1, sel, act, outp);
  for (int r = 1; r < NRND; ++r){
    ull* bcur = (r & 1) ? b1 : b0;                         // r=1 -> b1 (INF-init by stage1)
    ull* bnxt = (r & 1) ? b0 : b1;
    k_scanmerge<<<gv, 1024, 0, stream>>>(wf, L, par, bcur, bnxt, act, r);
    k_hook     <<<gv, 1024, 0, stream>>>(L, bcur, par, sel, act, r);
  }
  k_cnt    <<<Bc*BPB, 1024, 0, stream>>>(sel, blkcnt);
  k_scatter<<<Bc*BPB, 1024, 0, stream>>>(sel, blkcnt, outp);
}

// Round 14
// 206.016 us; speedup vs baseline: 1.1841x; 1.1418x over previous
//
#include <hip/hip_runtime.h>
#include <stdint.h>

typedef unsigned long long ull;
typedef unsigned short u16;

#define Bc 8
#define Cc 64
#define Hc 256
#define Wc 256
#define Vc (Hc*Wc)            // 65536
#define REc ((Hc-1)*Wc)       // 65280 row (down) edges
#define Ec (REc + Hc*(Wc-1))  // 130560 total edges
#define VM1 (Vc-1)            // 65535
#define INF64 0xFFFFFFFFFFFFFFFFull
#define TS 32                 // tile side
#define NRND 14               // rounds r=1..13: 13 hooks cover <=7936 comps (124/tile bound)
#define EPB 8192              // edges per block in compaction
#define BPB 16                // blocks per batch

__device__ __forceinline__ void edge_uv(int e, int& u, int& v){
  if (e < REc){ u = e; v = e + Wc; }
  else { int k = e - REc; int i = k / (Wc-1); int j = k - i*(Wc-1); u = i*Wc + j; v = u + 1; }
}

__device__ __forceinline__ ull packw(float w, int e){
  return ((ull)__float_as_uint(w) << 32) | (unsigned)e;
}

__device__ __forceinline__ int chase(const int* __restrict__ parB, int x){
  int p = parB[x];
  while (p != x){ x = p; p = parB[x]; }
  return x;
}

// ---------------- stage 1: weights + tile-local Boruvka (guarded LDS atomics) ----------------
// One WG per 32x32 tile. Freeze rule: a component selects/hooks only if its min
// incident edge is tile-internal (cut property => globally correct MST edges).
__global__ void __launch_bounds__(1024)
k_stage1(const float* __restrict__ g, float* __restrict__ wf,
         int* __restrict__ L, int* __restrict__ par, ull* __restrict__ b1,
         unsigned char* __restrict__ sel, int* __restrict__ act, int* __restrict__ outp){
  const int blk = blockIdx.x;
  const int b = blk >> 6, tile = blk & 63;
  const int ty = tile >> 3, tx = tile & 7;
  const int tid = threadIdx.x;
  const int li = tid >> 5, lj = tid & 31;
  const int i = ty*TS + li, j = tx*TS + lj;
  const int v = (i << 8) | j;

  // --- 4-direction edge weights (sequential c order: bit-exact vs reference) ---
  const bool hU = i > 0, hD = i < Hc-1, hL = j > 0, hR = j < Wc-1;
  const int oU = hU ? -Wc : 0, oD = hD ? Wc : 0, oL = hL ? -1 : 0, oR = hR ? 1 : 0;
  const float* p = g + (size_t)b*Cc*Vc + v;
  float sU=0.f, sD=0.f, sL=0.f, sR=0.f;
  #pragma unroll 8
  for (int c = 0; c < Cc; ++c){
    const float* pc = p + (size_t)c*Vc;
    float x = pc[0];
    float dU = x - pc[oU]; float dD = x - pc[oD];          // (a-b)^2 == (b-a)^2 bitwise
    float dL = x - pc[oL]; float dR = x - pc[oR];
    sU += dU*dU; sD += dD*dD; sL += dL*dL; sR += dR*dR;
  }
  const int eU = v - Wc, eD = v, eL = REc + i*(Wc-1) + j - 1, eR = REc + i*(Wc-1) + j;
  const ull pU = packw(sU+1.f, eU), pD = packw(sD+1.f, eD);
  const ull pL = packw(sL+1.f, eL), pR = packw(sR+1.f, eR);
  float* wfb = wf + (size_t)b*Ec;
  unsigned char* selb = sel + (size_t)b*Ec;
  if (hD){ wfb[eD] = sD+1.f; selb[eD] = 0; }               // canonical owner writes
  if (hR){ wfb[eR] = sR+1.f; selb[eR] = 0; }
  { int gt = blk*1024 + tid;
    if (gt < Bc*VM1){ outp[2*gt] = 0; outp[2*gt+1] = Wc; } // ref fill value (edge 0)
    if (gt < (NRND+2)*Bc) act[gt] = (gt >= Bc && gt < 2*Bc) ? 1 : 0; // act[1][*]=1
  }

  // --- tile-local Boruvka with freeze rule (R7/R10-verified; guarded atomics) ---
  __shared__ u16 lab[1024];
  __shared__ u16 spar[1024];
  __shared__ ull best[1024];
  __shared__ int s_any;
  lab[tid] = (u16)tid;

  for (int round = 0; round < 16; ++round){
    best[tid] = INF64;
    if (tid == 0) s_any = 0;
    __syncthreads();
    int c = lab[tid];
    ull m = INF64;
    if (hU){ bool inc = (li > 0)    ? (lab[tid-TS] != c) : true; if (inc && pU < m) m = pU; }
    if (hD){ bool inc = (li < TS-1) ? (lab[tid+TS] != c) : true; if (inc && pD < m) m = pD; }
    if (hL){ bool inc = (lj > 0)    ? (lab[tid-1 ] != c) : true; if (inc && pL < m) m = pL; }
    if (hR){ bool inc = (lj < TS-1) ? (lab[tid+1 ] != c) : true; if (inc && pR < m) m = pR; }
    if (round == 0){
      best[tid] = m;                                       // singleton comps: single writer
    } else if (m != INF64 && m < best[c]){                 // guarded: slot values only decrease
      atomicMin(&best[c], m);
    }
    __syncthreads();
    int pr = tid;
    if (c == tid){                                         // root of a live component
      ull pb = best[tid];
      if (pb != INF64){
        int e = (int)(unsigned)pb; int eu, ev; edge_uv(e, eu, ev);
        int diu = (eu>>8) - ty*TS, dju = (eu&255) - tx*TS;
        int div_ = (ev>>8) - ty*TS, djv = (ev&255) - tx*TS;
        bool inu  = ((unsigned)diu < TS) && ((unsigned)dju < TS);
        bool inv_ = ((unsigned)div_ < TS) && ((unsigned)djv < TS);
        if (inu && inv_){                                  // internal: select + hook
          int lu = diu*TS + dju, lv = div_*TS + djv;
          int cu = lab[lu], cv = lab[lv];
          int other = (cu == tid) ? cv : cu;
          sel[(size_t)b*Ec + e] = 1;
          s_any = 1;
          pr = (best[other] == pb && tid < other) ? tid : other;
        }                                                  // else boundary: freeze
      }
    }
    spar[tid] = (u16)pr;
    __syncthreads();
    int x = lab[tid];
    int pp = spar[x];
    while (pp != x){ x = pp; pp = spar[x]; }               // read-only chase, acyclic
    int any = s_any;
    lab[tid] = (u16)x;
    __syncthreads();
    if (!any) break;
  }

  // --- tail: int labels (global root vertex id), identity par, INF b1 ---
  int rt = lab[tid];
  int groot = ((ty*TS + (rt>>5)) << 8) | (tx*TS + (rt&31));
  const int t = (b << 16) | v;
  L[t] = groot;                                            // root vertex has L[t]==v
  par[t] = v;                                              // identity hook forest
  b1[t] = INF64;                                           // round-1 minima buffer
}

// rounds >=1 (R6-proven): fused {relabel to hook-forest root} + {vertex scan},
// root-only reset of next buffer, settled-interior fast path, guarded global atomic.
__global__ void __launch_bounds__(1024)
k_scanmerge(const float* __restrict__ wf, int* __restrict__ L,
            const int* __restrict__ par,
            ull* __restrict__ bcur, ull* __restrict__ bnxt,
            const int* __restrict__ act, int r){
  int t = blockIdx.x*1024 + threadIdx.x;
  int b = t >> 16;
  if (!act[r*Bc + b]) return;
  int v = t & VM1; const int base = b << 16;
  const int* parB = par + base;
  int Lt0 = L[t];
  int i = v >> 8, j = v & (Wc-1);
  int Lu = (i > 0)    ? L[base + v - Wc] : Lt0;
  int Ld = (i < Hc-1) ? L[base + v + Wc] : Lt0;
  int Ll = (j > 0)    ? L[base + v - 1 ] : Lt0;
  int Lr = (j < Wc-1) ? L[base + v + 1 ] : Lt0;
  if ((Lu==Lt0) & (Ld==Lt0) & (Ll==Lt0) & (Lr==Lt0)){      // settled neighborhood
    if (Lt0 != v) return;                                  // interior non-root: done
    if (parB[v] == v){ bnxt[t] = INF64; return; }          // true root: reset next buf
    /* dead root (stale self-label): fall through to refresh L */
  }
  int rt = chase(parB, Lt0);
  if (rt != Lt0) L[t] = rt;                                // racy-read-benign: readers re-chase
  if (v == rt) bnxt[t] = INF64;                            // root-only reset for round r+1
  const float* wfb = wf + (size_t)b*Ec;
  ull m = INF64;
  if (Lu != Lt0 && Lu != rt && chase(parB, Lu) != rt){
    int e = v - Wc; ull x = packw(wfb[e], e); if (x < m) m = x; }
  if (Ld != Lt0 && Ld != rt && chase(parB, Ld) != rt){
    int e = v;      ull x = packw(wfb[e], e); if (x < m) m = x; }
  if (Ll != Lt0 && Ll != rt && chase(parB, Ll) != rt){
    int e = REc + i*(Wc-1) + j - 1; ull x = packw(wfb[e], e); if (x < m) m = x; }
  if (Lr != Lt0 && Lr != rt && chase(parB, Lr) != rt){
    int e = REc + i*(Wc-1) + j;     ull x = packw(wfb[e], e); if (x < m) m = x; }
  if (m != INF64 && m < bcur[base + rt])                   // guarded: monotone-decreasing slot
    atomicMin(&bcur[base + rt], m);
}

// roots pick best edge, mutual-pair break (smaller id stays root), write par + sel
__global__ void __launch_bounds__(1024)
k_hook(const int* __restrict__ L, const ull* __restrict__ bcur,
       int* __restrict__ par, unsigned char* __restrict__ sel, int* __restrict__ act, int r){
  int t = blockIdx.x*1024 + threadIdx.x;
  int b = t >> 16;
  if (!act[r*Bc + b]) return;
  int v = t & VM1;
  if (L[t] != v) return;                                   // roots only (L fresh for roots)
  const int base = b << 16;
  ull p = bcur[t];
  int pr = v;
  if (p != INF64){
    int e = (int)(unsigned)p; int eu, ev; edge_uv(e, eu, ev);
    int cu = L[base + eu], cv = L[base + ev];
    int other = (cu == v) ? cv : cu;
    sel[(size_t)b*Ec + e] = 1;
    if (act[(r+1)*Bc + b] == 0) act[(r+1)*Bc + b] = 1;     // read-guarded, benign race
    pr = (bcur[base + other] == p && v < other) ? v : other;
  }
  par[t] = pr;
}

// ---- ordered output compaction: count -> scatter (R6-proven) ----
__global__ void __launch_bounds__(1024)
k_cnt(const unsigned char* __restrict__ sel, int* __restrict__ blkcnt){
  int blk = blockIdx.x; int bb = blk / BPB; int kb = blk % BPB;
  int base = kb*EPB;
  int off = threadIdx.x * 8;
  int c = 0;
  if (base + off < Ec){
    const unsigned int* p = (const unsigned int*)(sel + (size_t)bb*Ec + base + off);
    unsigned int s = p[0] + p[1];                          // per-byte sums <=2, no carry
    c = (s & 0xFF) + ((s>>8)&0xFF) + ((s>>16)&0xFF) + (s>>24);
  }
  int lane = threadIdx.x & 63, wave = threadIdx.x >> 6;
  #pragma unroll
  for (int o = 32; o; o >>= 1) c += __shfl_down(c, o, 64);
  __shared__ int sw[16];
  if (lane == 0) sw[wave] = c;
  __syncthreads();
  if (threadIdx.x == 0){
    int s = 0;
    #pragma unroll
    for (int w = 0; w < 16; ++w) s += sw[w];
    blkcnt[blk] = s;
  }
}

__global__ void __launch_bounds__(1024)
k_scatter(const unsigned char* __restrict__ sel, const int* __restrict__ blkcnt,
          int* __restrict__ outp){
  int blk = blockIdx.x; int bb = blk / BPB; int kb = blk % BPB;
  __shared__ int s_boff;
  if (threadIdx.x < 64){                                   // wave 0: prefix of batch counts
    int c = ((int)threadIdx.x < kb) ? blkcnt[bb*BPB + threadIdx.x] : 0;
    #pragma unroll
    for (int o = 32; o; o >>= 1) c += __shfl_down(c, o, 64);
    if (threadIdx.x == 0) s_boff = c;
  }
  int base = kb*EPB;
  int off = threadIdx.x * 8;
  unsigned int a = 0, d = 0; int c = 0;
  if (base + off < Ec){
    const unsigned int* p = (const unsigned int*)(sel + (size_t)bb*Ec + base + off);
    a = p[0]; d = p[1];
    unsigned int s = a + d;
    c = (s & 0xFF) + ((s>>8)&0xFF) + ((s>>16)&0xFF) + (s>>24);
  }
  int lane = threadIdx.x & 63, wave = threadIdx.x >> 6;
  int x = c;
  #pragma unroll
  for (int o = 1; o < 64; o <<= 1){ int y = __shfl_up(x, o, 64); if (lane >= o) x += y; }
  __shared__ int sw[16];
  if (lane == 63) sw[wave] = x;
  __syncthreads();
  int woff = 0;
  #pragma unroll
  for (int w = 0; w < 16; ++w) if (w < wave) woff += sw[w];
  int pos = s_boff + woff + x - c;
  if (base + off < Ec){
    int* ob = outp + (size_t)bb*VM1*2;
    int ebase = base + off;
    #pragma unroll
    for (int k = 0; k < 8; ++k){
      unsigned int byte = ((k < 4) ? (a >> (8*k)) : (d >> (8*(k-4)))) & 0xFF;
      if (byte){ int e = ebase + k; int u, v; edge_uv(e, u, v); ob[2*pos] = u; ob[2*pos+1] = v; ++pos; }
    }
  }
}

extern "C" void kernel_launch(void* const* d_in, const int* in_sizes, int n_in,
                              void* d_out, int out_size, void* d_ws, size_t ws_size,
                              hipStream_t stream) {
  const float* g = (const float*)d_in[0];
  int* outp = (int*)d_out;

  char* ws = (char*)d_ws;
  size_t off = 0;
  auto alloc = [&](size_t bytes) -> void* {
    void* p = ws + off; off += (bytes + 511) & ~(size_t)511; return p;
  };
  ull* b0 = (ull*)alloc((size_t)Bc*Vc*8);
  ull* b1 = (ull*)alloc((size_t)Bc*Vc*8);
  float* wf = (float*)alloc((size_t)Bc*Ec*4);
  int* L   = (int*)alloc((size_t)Bc*Vc*4);
  int* par = (int*)alloc((size_t)Bc*Vc*4);
  unsigned char* sel = (unsigned char*)alloc((size_t)Bc*Ec);
  int* act  = (int*)alloc((size_t)(NRND+2)*Bc*4);
  int* blkcnt = (int*)alloc((size_t)Bc*BPB*4);

  const int gv = (Bc*Vc)/1024;                             // 512 WGs, 1024-thr

  k_stage1<<<Bc*64, 1024, 0, stream>>>(g, wf, L, par, b1, sel, act, outp);
  for (int r = 1; r < NRND; ++r){
    ull* bcur = (r & 1) ? b1 : b0;                         // r=1 -> b1 (INF-init by stage1)
    ull* bnxt = (r & 1) ? b0 : b1;
    k_scanmerge<<<gv, 1024, 0, stream>>>(wf, L, par, bcur, bnxt, act, r);
    k_hook     <<<gv, 1024, 0, stream>>>(L, bcur, par, sel, act, r);
  }
  k_cnt    <<<Bc*BPB, 1024, 0, stream>>>(sel, blkcnt);
  k_scatter<<<Bc*BPB, 1024, 0, stream>>>(sel, blkcnt, outp);
}